// Round 1
// baseline (28927.148 us; speedup 1.0000x reference)
//
#include <hip/hip_runtime.h>
#include <hip/hip_fp16.h>

#define N_ 256
#define C_ 3
#define T_ 300
#define V_ 25
#define H_ 256
#define G4_ 1024   // 4*H
#define IN_ 75
#define XP1_ 96    // padded input-K for seq (phase1 / m0)
#define NCLS_ 60

typedef _Float16 half_t;
typedef __attribute__((ext_vector_type(8))) _Float16 half8;
typedef __attribute__((ext_vector_type(4))) float f32x4;

static_assert(sizeof(half8) == 16, "half8 must be 16B");

__device__ __forceinline__ float sigm(float x) { return 1.0f / (1.0f + __expf(-x)); }
__device__ __forceinline__ float tanh_f(float x) {
  x = fminf(fmaxf(x, -15.0f), 15.0f);
  float e = __expf(2.0f * x);
  return (e - 1.0f) / (e + 1.0f);
}

// ---------- pack [Whh | Wih | 0pad] rows into fp16, and bias = bih+bhh ----------
__global__ void pack_wcat(const float* __restrict__ Whh, const float* __restrict__ Wih,
                          const float* __restrict__ bih, const float* __restrict__ bhh,
                          half_t* __restrict__ dstW, float* __restrict__ dstB,
                          int inDim, int Kc) {
  int idx = blockIdx.x * 256 + threadIdx.x;
  int tot = G4_ * Kc;
  if (idx < tot) {
    int row = idx / Kc, k = idx % Kc;
    float v = 0.0f;
    if (k < H_) v = Whh[row * H_ + k];
    else if (k - H_ < inDim) v = Wih[row * inDim + (k - H_)];
    dstW[idx] = (half_t)v;
  }
  if (idx < G4_) dstB[idx] = bih[idx] + bhh[idx];
}

// ---------- pack x -> seqb[p][n][t][96] fp16 (k = c*25+v, zero pad) ----------
__global__ void pack_seq(const float* __restrict__ x, half_t* __restrict__ seqb) {
  int idx = blockIdx.x * 256 + threadIdx.x;   // over 2*256*300*96 = 14,745,600
  const int tot = 2 * N_ * T_ * XP1_;
  if (idx >= tot) return;
  int k = idx % XP1_; int r = idx / XP1_;
  int t = r % T_; int r2 = r / T_;
  int n = r2 % N_; int p = r2 / N_;
  float v = 0.0f;
  if (k < IN_) {
    int c = k / V_, vv = k % V_;
    v = x[(((size_t)n * C_ + c) * T_ + t) * (V_ * 2) + vv * 2 + p];
  }
  seqb[idx] = (half_t)v;
}

// ---------- the recurrent workhorse ----------
// One WG = 16 samples, full H. A=[h_t ; x_t] (K = NKT*32), B = Wcat streamed from L2.
// hls double-buffered, XOR-swizzled (T2) against the 512B-row-stride bank conflict.
template<int NKT>
__global__ __launch_bounds__(256, 1) void lstm_kernel(
    const half_t* __restrict__ WcatA, const half_t* __restrict__ WcatB,
    const float* __restrict__ biasA, const float* __restrict__ biasB,
    const half_t* xseq, int XK,
    half_t* hseqA, half_t* hseqB,
    float* hlastA, float* hlastB,
    int blocksPerRun) {
  constexpr int Kc = NKT * 32;
  const int cb = blockIdx.x;
  const int run = cb / blocksPerRun;
  const int lb = cb % blocksPerRun;
  const int p = lb >> 4;
  const int n0 = (lb & 15) << 4;

  const half_t* __restrict__ Wcat = run ? WcatB : WcatA;
  const float* __restrict__ bias = run ? biasB : biasA;
  half_t* hseq = run ? hseqB : hseqA;
  float* hlast = run ? hlastB : hlastA;

  const int lane = threadIdx.x & 63;
  const int wave = threadIdx.x >> 6;
  const int col = lane & 15;          // A-row (sample) / B-col (gate) / D-col
  const int khalf = lane >> 4;        // k-chunk selector; D-row block
  const int klo = khalf << 3;

  __shared__ __align__(16) unsigned short hls[2][16 * 256];
  for (int i = threadIdx.x; i < 16 * 256; i += 256) hls[0][i] = 0;
  __syncthreads();

  // per-lane constants: bias + weight-row pointers for [uu][gate]
  float brg[4][4];
  const half_t* wrow[4][4];
#pragma unroll
  for (int uu = 0; uu < 4; ++uu)
#pragma unroll
    for (int g = 0; g < 4; ++g) {
      int j = g * 256 + (wave * 4 + uu) * 16 + col;
      brg[uu][g] = bias[j];
      wrow[uu][g] = Wcat + (size_t)j * Kc + klo;
    }

  const half_t* xrow = xseq + ((size_t)(p * N_ + n0 + col) * T_) * XK + klo;
  const size_t srow0 = (size_t)(p * N_ + n0);

  float creg[4][4] = {};  // cell state [uu][r]

#pragma unroll 1
  for (int t = 0; t < T_; ++t) {
    const int cur = t & 1;
    // gather A-fragments once per step (h from LDS, x from global)
    half8 a[NKT];
#pragma unroll
    for (int kt = 0; kt < NKT; ++kt) {
      if (kt < 8) {
        int u = ((col << 8) + (kt << 5) + klo) ^ ((col & 7) << 3);
        a[kt] = *reinterpret_cast<const half8*>(&hls[cur][u]);
      } else {
        a[kt] = *reinterpret_cast<const half8*>(xrow + (size_t)t * XK + ((kt - 8) << 5));
      }
    }
    __syncthreads();  // allows safe in-place hseq overwrite (m1/m2)

#pragma unroll
    for (int uu = 0; uu < 4; ++uu) {
      f32x4 acc[4];
#pragma unroll
      for (int g = 0; g < 4; ++g) {
        float b = brg[uu][g];
        acc[g] = (f32x4){b, b, b, b};
      }
#pragma unroll
      for (int kt = 0; kt < NKT; ++kt) {
#pragma unroll
        for (int g = 0; g < 4; ++g) {
          half8 bfr = *reinterpret_cast<const half8*>(wrow[uu][g] + kt * 32);
          acc[g] = __builtin_amdgcn_mfma_f32_16x16x32_f16(a[kt], bfr, acc[g], 0, 0, 0);
        }
      }
      const int unit = (wave * 4 + uu) * 16 + col;
#pragma unroll
      for (int r = 0; r < 4; ++r) {
        const int s = khalf * 4 + r;
        float iv = sigm(acc[0][r]);
        float fv = sigm(acc[1][r]);
        float gv = tanh_f(acc[2][r]);
        float ov = sigm(acc[3][r]);
        float c = fv * creg[uu][r] + iv * gv;
        creg[uu][r] = c;
        float h = ov * tanh_f(c);
        int u = ((s << 8) + unit) ^ ((s & 7) << 3);
        half_t hh = (half_t)h;
        hls[cur ^ 1][u] = __builtin_bit_cast(unsigned short, hh);
        if (hseq) hseq[((srow0 + s) * T_ + t) * H_ + unit] = hh;
        if (hlast && t == T_ - 1) hlast[(srow0 + s) * H_ + unit] = h;
      }
    }
    __syncthreads();
  }
}

// ---------- angles/trans FC + rotation matrices ----------
__global__ void fc3_rot(const float* __restrict__ hrot, const float* __restrict__ htr,
                        const float* __restrict__ rfcW, const float* __restrict__ rfcb,
                        const float* __restrict__ tfcW, const float* __restrict__ tfcb,
                        float* __restrict__ rt) {
  int idx = blockIdx.x * blockDim.x + threadIdx.x;  // (p*256+n)
  if (idx >= 2 * N_) return;
  const float* h1 = hrot + (size_t)idx * H_;
  const float* h2 = htr + (size_t)idx * H_;
  float ang[3], tr[3];
#pragma unroll
  for (int i = 0; i < 3; ++i) {
    float a = rfcb[i], b = tfcb[i];
    for (int j = 0; j < H_; ++j) { a += h1[j] * rfcW[i * H_ + j]; b += h2[j] * tfcW[i * H_ + j]; }
    ang[i] = a * 3.14159265358979323846f;
    tr[i] = b;
  }
  float c0 = cosf(ang[0]), s0 = sinf(ang[0]);
  float c1 = cosf(ang[1]), s1 = sinf(ang[1]);
  float c2 = cosf(ang[2]), s2 = sinf(ang[2]);
  float Rx[3][3] = {{1, 0, 0}, {0, c0, s0}, {0, -s0, c0}};
  float Ry[3][3] = {{c1, 0, -s1}, {0, 1, 0}, {s1, 0, c1}};
  float Rz[3][3] = {{c2, s2, 0}, {-s2, c2, 0}, {0, 0, 1}};
  float A[3][3], R[3][3];
  for (int i = 0; i < 3; ++i)
    for (int j = 0; j < 3; ++j) {
      float s = 0;
      for (int k = 0; k < 3; ++k) s += Rx[i][k] * Ry[k][j];
      A[i][j] = s;
    }
  for (int i = 0; i < 3; ++i)
    for (int j = 0; j < 3; ++j) {
      float s = 0;
      for (int k = 0; k < 3; ++k) s += A[i][k] * Rz[k][j];
      R[i][j] = s;
    }
  float* o = rt + (size_t)idx * 12;
  for (int i = 0; i < 9; ++i) o[i] = R[i / 3][i % 3];
  for (int i = 0; i < 3; ++i) o[9 + i] = tr[i];
}

// ---------- seq2 = R @ (x - trans), written over seqb ----------
__global__ void transform_seq(const float* __restrict__ x, const float* __restrict__ rt,
                              half_t* __restrict__ seqb) {
  int idx = blockIdx.x * 256 + threadIdx.x;  // over 2*256*300*25 = 3,840,000
  const int tot = 2 * N_ * T_ * V_;
  if (idx >= tot) return;
  int v = idx % V_; int r = idx / V_;
  int t = r % T_; int r2 = r / T_;
  int n = r2 % N_; int p = r2 / N_;
  const float* o = rt + ((size_t)p * N_ + n) * 12;
  float xv[3];
#pragma unroll
  for (int c = 0; c < 3; ++c)
    xv[c] = x[(((size_t)n * C_ + c) * T_ + t) * (V_ * 2) + v * 2 + p] - o[9 + c];
  size_t base = (((size_t)p * N_ + n) * T_ + t) * XP1_;
#pragma unroll
  for (int i = 0; i < 3; ++i) {
    float s = o[i * 3 + 0] * xv[0] + o[i * 3 + 1] * xv[1] + o[i * 3 + 2] * xv[2];
    seqb[base + i * V_ + v] = (half_t)s;
  }
}

// ---------- maxpool over persons + final FC ----------
__global__ void final_fc(const float* __restrict__ hM2, const float* __restrict__ fcW,
                         const float* __restrict__ fcb, float* __restrict__ out) {
  int n = blockIdx.x;
  __shared__ float hm[H_];
  for (int j = threadIdx.x; j < H_; j += blockDim.x)
    hm[j] = fmaxf(hM2[(size_t)n * H_ + j], hM2[(size_t)(N_ + n) * H_ + j]);
  __syncthreads();
  if (threadIdx.x < NCLS_) {
    float acc = fcb[threadIdx.x];
    for (int j = 0; j < H_; ++j) acc += hm[j] * fcW[threadIdx.x * H_ + j];
    out[n * NCLS_ + threadIdx.x] = acc;
  }
}

extern "C" void kernel_launch(void* const* d_in, const int* in_sizes, int n_in,
                              void* d_out, int out_size, void* d_ws, size_t ws_size,
                              hipStream_t stream) {
  const float* x       = (const float*)d_in[0];
  const float* rot_Wih = (const float*)d_in[1];
  const float* rot_Whh = (const float*)d_in[2];
  const float* rot_bih = (const float*)d_in[3];
  const float* rot_bhh = (const float*)d_in[4];
  const float* rot_fcW = (const float*)d_in[5];
  const float* rot_fcb = (const float*)d_in[6];
  const float* tr_Wih  = (const float*)d_in[7];
  const float* tr_Whh  = (const float*)d_in[8];
  const float* tr_bih  = (const float*)d_in[9];
  const float* tr_bhh  = (const float*)d_in[10];
  const float* tr_fcW  = (const float*)d_in[11];
  const float* tr_fcb  = (const float*)d_in[12];
  const float* m0_Wih  = (const float*)d_in[13];
  const float* m0_Whh  = (const float*)d_in[14];
  const float* m0_bih  = (const float*)d_in[15];
  const float* m0_bhh  = (const float*)d_in[16];
  const float* m1_Wih  = (const float*)d_in[17];
  const float* m1_Whh  = (const float*)d_in[18];
  const float* m1_bih  = (const float*)d_in[19];
  const float* m1_bhh  = (const float*)d_in[20];
  const float* m2_Wih  = (const float*)d_in[21];
  const float* m2_Whh  = (const float*)d_in[22];
  const float* m2_bih  = (const float*)d_in[23];
  const float* m2_bhh  = (const float*)d_in[24];
  const float* fcW     = (const float*)d_in[25];
  const float* fcb     = (const float*)d_in[26];

  char* ws = (char*)d_ws;
  size_t off = 0;
  auto take = [&](size_t b) -> void* {
    void* pp = ws + off;
    off = (off + b + 255) & ~(size_t)255;
    return pp;
  };
  half_t* WC_ROT = (half_t*)take((size_t)G4_ * 352 * 2);
  half_t* WC_TR  = (half_t*)take((size_t)G4_ * 352 * 2);
  half_t* WC_M0  = (half_t*)take((size_t)G4_ * 352 * 2);
  half_t* WC_M1  = (half_t*)take((size_t)G4_ * 512 * 2);
  half_t* WC_M2  = (half_t*)take((size_t)G4_ * 512 * 2);
  float* B_ROT = (float*)take((size_t)G4_ * 4);
  float* B_TR  = (float*)take((size_t)G4_ * 4);
  float* B_M0  = (float*)take((size_t)G4_ * 4);
  float* B_M1  = (float*)take((size_t)G4_ * 4);
  float* B_M2  = (float*)take((size_t)G4_ * 4);
  half_t* SEQB = (half_t*)take((size_t)2 * N_ * T_ * XP1_ * 2);
  float* HL_ROT = (float*)take((size_t)2 * N_ * H_ * 4);
  float* HL_TR  = (float*)take((size_t)2 * N_ * H_ * 4);
  float* HL_M2  = (float*)take((size_t)2 * N_ * H_ * 4);
  float* RT     = (float*)take((size_t)2 * N_ * 12 * 4);
  half_t* HSEQ  = (half_t*)take((size_t)2 * N_ * T_ * H_ * 2);

  // ---- pack weights (fp16) + fused biases ----
  pack_wcat<<<1408, 256, 0, stream>>>(rot_Whh, rot_Wih, rot_bih, rot_bhh, WC_ROT, B_ROT, IN_, 352);
  pack_wcat<<<1408, 256, 0, stream>>>(tr_Whh, tr_Wih, tr_bih, tr_bhh, WC_TR, B_TR, IN_, 352);
  pack_wcat<<<1408, 256, 0, stream>>>(m0_Whh, m0_Wih, m0_bih, m0_bhh, WC_M0, B_M0, IN_, 352);
  pack_wcat<<<2048, 256, 0, stream>>>(m1_Whh, m1_Wih, m1_bih, m1_bhh, WC_M1, B_M1, H_, 512);
  pack_wcat<<<2048, 256, 0, stream>>>(m2_Whh, m2_Wih, m2_bih, m2_bhh, WC_M2, B_M2, H_, 512);

  // ---- pack input sequence ----
  pack_seq<<<(2 * N_ * T_ * XP1_ + 255) / 256, 256, 0, stream>>>(x, SEQB);

  // ---- phase 1: rot & tr LSTMs in one launch (2 runs x 2 persons x 16 blocks) ----
  lstm_kernel<11><<<64, 256, 0, stream>>>(WC_ROT, WC_TR, B_ROT, B_TR, SEQB, XP1_,
                                          nullptr, nullptr, HL_ROT, HL_TR, 32);

  // ---- angles, translation, rotation matrices ----
  fc3_rot<<<2, 256, 0, stream>>>(HL_ROT, HL_TR, rot_fcW, rot_fcb, tr_fcW, tr_fcb, RT);

  // ---- view transform (overwrites SEQB with seq2) ----
  transform_seq<<<(2 * N_ * T_ * V_ + 255) / 256, 256, 0, stream>>>(x, RT, SEQB);

  // ---- stacked main LSTMs (HSEQ reused in-place between layers) ----
  lstm_kernel<11><<<32, 256, 0, stream>>>(WC_M0, WC_M0, B_M0, B_M0, SEQB, XP1_,
                                          HSEQ, HSEQ, nullptr, nullptr, 32);
  lstm_kernel<16><<<32, 256, 0, stream>>>(WC_M1, WC_M1, B_M1, B_M1, HSEQ, H_,
                                          HSEQ, HSEQ, nullptr, nullptr, 32);
  lstm_kernel<16><<<32, 256, 0, stream>>>(WC_M2, WC_M2, B_M2, B_M2, HSEQ, H_,
                                          nullptr, nullptr, HL_M2, HL_M2, 32);

  // ---- maxpool + classifier ----
  final_fc<<<256, 64, 0, stream>>>(HL_M2, fcW, fcb, (float*)d_out);
}

// Round 2
// 25548.134 us; speedup vs baseline: 1.1323x; 1.1323x over previous
//
#include <hip/hip_runtime.h>
#include <hip/hip_fp16.h>

#define N_ 256
#define C_ 3
#define T_ 300
#define V_ 25
#define H_ 256
#define G4_ 1024   // 4*H
#define IN_ 75
#define XP1_ 96    // padded input-K
#define NCLS_ 60
#define NRING 512  // sample rows per run in ring

typedef _Float16 half_t;
typedef __attribute__((ext_vector_type(8))) _Float16 half8;
typedef __attribute__((ext_vector_type(4))) float f32x4;

static_assert(sizeof(half8) == 16, "half8 must be 16B");

__device__ __forceinline__ float sigm(float x) { return 1.0f / (1.0f + __expf(-x)); }
__device__ __forceinline__ float tanh_f(float x) {
  x = fminf(fmaxf(x, -15.0f), 15.0f);
  float e = __expf(2.0f * x);
  return (e - 1.0f) / (e + 1.0f);
}

__device__ __forceinline__ half8 zero8() {
  half8 z = {(half_t)0,(half_t)0,(half_t)0,(half_t)0,(half_t)0,(half_t)0,(half_t)0,(half_t)0};
  return z;
}

// ---------- pack [Whh | Wih | 0pad] rows into fp16, bias = bih+bhh ----------
__global__ void pack_wcat(const float* __restrict__ Whh, const float* __restrict__ Wih,
                          const float* __restrict__ bih, const float* __restrict__ bhh,
                          half_t* __restrict__ dstW, float* __restrict__ dstB,
                          int inDim, int Kc) {
  int idx = blockIdx.x * 256 + threadIdx.x;
  int tot = G4_ * Kc;
  if (idx < tot) {
    int row = idx / Kc, k = idx % Kc;
    float v = 0.0f;
    if (k < H_) v = Whh[row * H_ + k];
    else if (k - H_ < inDim) v = Wih[row * inDim + (k - H_)];
    dstW[idx] = (half_t)v;
  }
  if (idx < G4_) dstB[idx] = bih[idx] + bhh[idx];
}

// ---------- pack x -> seqb[p][n][t][96] fp16 ----------
__global__ void pack_seq(const float* __restrict__ x, half_t* __restrict__ seqb) {
  int idx = blockIdx.x * 256 + threadIdx.x;
  const int tot = 2 * N_ * T_ * XP1_;
  if (idx >= tot) return;
  int k = idx % XP1_; int r = idx / XP1_;
  int t = r % T_; int r2 = r / T_;
  int n = r2 % N_; int p = r2 / N_;
  float v = 0.0f;
  if (k < IN_) {
    int c = k / V_, vv = k % V_;
    v = x[(((size_t)n * C_ + c) * T_ + t) * (V_ * 2) + vv * 2 + p];
  }
  seqb[idx] = (half_t)v;
}

// ---------- group barrier: 8 WGs, flag-based, cross-XCD safe ----------
__device__ __forceinline__ void group_sync(unsigned int* cnt, unsigned int target) {
  __syncthreads();                       // all stores issued (vmcnt drained at barrier)
  if (threadIdx.x == 0) {
    __threadfence();                     // release: writeback to coherent point
    __hip_atomic_fetch_add(cnt, 1u, __ATOMIC_RELAXED, __HIP_MEMORY_SCOPE_AGENT);
    int guard = 0;
    while (__hip_atomic_load(cnt, __ATOMIC_RELAXED, __HIP_MEMORY_SCOPE_AGENT) < target) {
      __builtin_amdgcn_s_sleep(2);
      if (++guard > (1 << 22)) break;    // safety: avoid infinite hang
    }
    __threadfence();                     // acquire: invalidate stale L1/L2
  }
  __syncthreads();
}

// ---------- cooperative LSTM ----------
// grid = 256 WGs = 8 members (gate slices of 32 units) x 32 groups.
// Member m of group g is blockIdx = m*32 + g  (same XCD under round-robin).
// Weights slice (128 rows x Kc) lives in LDS, fragment-linear, loaded once.
// h exchanged per step through global ring[2][NRING][H] + group_sync.
template<int KT, int MT>
__global__ __launch_bounds__(256, 1) void lstm_coop(
    const half_t* __restrict__ WcatA, const half_t* __restrict__ WcatB,
    const float* __restrict__ biasA, const float* __restrict__ biasB,
    const half_t* __restrict__ xseqA, const half_t* __restrict__ xseqB, int XK,
    half_t* ringA, half_t* ringB,
    half_t* hseqA, half_t* hseqB,
    float* hlastA, float* hlastB,
    unsigned int* cnt, unsigned int baseCnt) {
  constexpr int HKT = 8;            // k-chunks holding h (256 = 8*32)
  constexpr int Kc = KT * 32;
  constexpr int M = MT * 16;        // samples per WG
  constexpr int NSG = 16 / MT;      // sample groups per person
  constexpr int PER_RUN = 2 * NSG;

  const int member = blockIdx.x >> 5;   // 0..7 : which 32-unit slice
  const int gidx   = blockIdx.x & 31;   // group id (also counter index)
  const int run = gidx / PER_RUN;
  const int rem = gidx % PER_RUN;
  const int p  = rem / NSG;
  const int sg = rem % NSG;
  const int srow0 = p * N_ + sg * M;
  const int u0 = member * 32;

  const half_t* __restrict__ Wcat = run ? WcatB : WcatA;
  const float*  __restrict__ bias = run ? biasB : biasA;
  const half_t* __restrict__ xseq = run ? xseqB : xseqA;
  half_t* ring  = run ? ringB : ringA;
  half_t* hseq  = run ? hseqB : hseqA;
  float*  hlast = run ? hlastB : hlastA;
  unsigned int* mycnt = cnt + gidx;

  const int tid = threadIdx.x;
  const int lane = tid & 63;
  const int wave = tid >> 6;
  const int col = lane & 15;
  const int khalf = lane >> 4;
  const int klo8 = khalf * 8;

  __shared__ __align__(16) half_t wlds[8 * KT * 64 * 8];
  __shared__ __align__(8)  half_t hstage[M * 32];

  // ---- one-time: weight slice -> LDS in fragment-linear layout ----
  // entry [nt][kt][l][e] = W[row = nt*16 + (l&15)][k = kt*32 + (l>>4)*8 + e]
  // local row r (0..127) maps to unit u = r>>2, gate g = r&3; global row g*256+u0+u
  for (int ci = tid; ci < 8 * KT * 64; ci += 256) {
    int nt = ci / (KT * 64);
    int r2 = ci % (KT * 64);
    int kt = r2 / 64;
    int l = r2 & 63;
    int lrow = nt * 16 + (l & 15);
    int grow = (lrow & 3) * 256 + u0 + (lrow >> 2);
    int k = kt * 32 + (l >> 4) * 8;
    *reinterpret_cast<half8*>(&wlds[(size_t)ci * 8]) =
        *reinterpret_cast<const half8*>(Wcat + (size_t)grow * Kc + k);
  }
  float brg[2];
#pragma unroll
  for (int ntp = 0; ntp < 2; ++ntp) {
    int lrow = (wave * 2 + ntp) * 16 + col;
    brg[ntp] = bias[(lrow & 3) * 256 + u0 + (lrow >> 2)];
  }
  __syncthreads();

  // per-lane base pointers
  const half_t* xrow0[MT];
#pragma unroll
  for (int mt = 0; mt < MT; ++mt)
    xrow0[mt] = xseq + (size_t)(srow0 + mt * 16 + col) * T_ * XK;

  float creg[MT][2][4] = {};
  const int g = col & 3;

#pragma unroll 1
  for (int t = 0; t < T_; ++t) {
    // ---- A fragments: h from ring[(t-1)&1] (zero at t=0), x from global ----
    half8 a[MT][KT];
    const half_t* hbase = ring + (size_t)((t & 1) ^ 1) * NRING * H_;
#pragma unroll
    for (int mt = 0; mt < MT; ++mt) {
      const half_t* hrow = hbase + (size_t)(srow0 + mt * 16 + col) * H_;
      const half_t* xrow = xrow0[mt] + (size_t)t * XK;
#pragma unroll
      for (int kt = 0; kt < KT; ++kt) {
        if (kt < HKT)
          a[mt][kt] = (t > 0) ? *reinterpret_cast<const half8*>(hrow + kt * 32 + klo8)
                              : zero8();
        else
          a[mt][kt] = *reinterpret_cast<const half8*>(xrow + (kt - HKT) * 32 + klo8);
      }
    }

    // ---- MFMA: acc[mt][ntp], B from LDS (conflict-free lane-linear) ----
    f32x4 acc[MT][2];
#pragma unroll
    for (int mt = 0; mt < MT; ++mt)
#pragma unroll
      for (int ntp = 0; ntp < 2; ++ntp)
        acc[mt][ntp] = (f32x4){brg[ntp], brg[ntp], brg[ntp], brg[ntp]};
#pragma unroll
    for (int kt = 0; kt < KT; ++kt) {
#pragma unroll
      for (int ntp = 0; ntp < 2; ++ntp) {
        int nt = wave * 2 + ntp;
        half8 bf = *reinterpret_cast<const half8*>(&wlds[(size_t)((nt * KT + kt) * 64 + lane) * 8]);
#pragma unroll
        for (int mt = 0; mt < MT; ++mt)
          acc[mt][ntp] = __builtin_amdgcn_mfma_f32_16x16x32_f16(a[mt][kt], bf, acc[mt][ntp], 0, 0, 0);
      }
    }

    // ---- activations + cell update (gates in 4 adjacent lanes) ----
#pragma unroll
    for (int mt = 0; mt < MT; ++mt) {
#pragma unroll
      for (int ntp = 0; ntp < 2; ++ntp) {
        int nt = wave * 2 + ntp;
        int ul = nt * 4 + (col >> 2);
#pragma unroll
        for (int r = 0; r < 4; ++r) {
          float v = acc[mt][ntp][r];
          // one exp for both: sigmoid(y) with y = (g==2 ? 2v : v); tanh = 2*sig(2v)-1
          float y = (g == 2) ? 2.0f * v : v;
          float s = 1.0f / (1.0f + __expf(-y));
          float av = (g == 2) ? (2.0f * s - 1.0f) : s;
          float b1 = __shfl_xor(av, 1);
          float b2 = __shfl_xor(av, 2);
          float b3 = __shfl_xor(b1, 2);
          // gate j value sits at index g^j in {av,b1,b2,b3}
          auto pick = [&](int k2) { return k2 == 0 ? av : (k2 == 1 ? b1 : (k2 == 2 ? b2 : b3)); };
          float iv = pick(g), fv = pick(g ^ 1), gv = pick(g ^ 2), ov = pick(g ^ 3);
          float c = fv * creg[mt][ntp][r] + iv * gv;
          creg[mt][ntp][r] = c;
          float h = ov * tanh_f(c);
          if (g == 0) {
            int s_ = mt * 16 + khalf * 4 + r;
            hstage[s_ * 32 + ul] = (half_t)h;
            if (hlast != nullptr && t == T_ - 1)
              hlast[(size_t)(srow0 + s_) * H_ + u0 + ul] = h;
          }
        }
      }
    }
    __syncthreads();

    // ---- coalesced write-out: ring (always) + hseq (optional) ----
    for (int i = tid; i < M * 16; i += 256) {
      int s_ = i >> 4, jj = (i & 15) * 2;
      unsigned int val = *reinterpret_cast<const unsigned int*>(&hstage[s_ * 32 + jj]);
      int srow = srow0 + s_;
      *reinterpret_cast<unsigned int*>(ring + ((size_t)(t & 1) * NRING + srow) * H_ + u0 + jj) = val;
      if (hseq)
        *reinterpret_cast<unsigned int*>(hseq + ((size_t)srow * T_ + t) * H_ + u0 + jj) = val;
    }

    group_sync(mycnt, baseCnt + 8u * (t + 1));
  }
}

// ---------- angles/trans FC + rotation matrices ----------
__global__ void fc3_rot(const float* __restrict__ hrot, const float* __restrict__ htr,
                        const float* __restrict__ rfcW, const float* __restrict__ rfcb,
                        const float* __restrict__ tfcW, const float* __restrict__ tfcb,
                        float* __restrict__ rt) {
  int idx = blockIdx.x * blockDim.x + threadIdx.x;
  if (idx >= 2 * N_) return;
  const float* h1 = hrot + (size_t)idx * H_;
  const float* h2 = htr + (size_t)idx * H_;
  float ang[3], tr[3];
#pragma unroll
  for (int i = 0; i < 3; ++i) {
    float a = rfcb[i], b = tfcb[i];
    for (int j = 0; j < H_; ++j) { a += h1[j] * rfcW[i * H_ + j]; b += h2[j] * tfcW[i * H_ + j]; }
    ang[i] = a * 3.14159265358979323846f;
    tr[i] = b;
  }
  float c0 = cosf(ang[0]), s0 = sinf(ang[0]);
  float c1 = cosf(ang[1]), s1 = sinf(ang[1]);
  float c2 = cosf(ang[2]), s2 = sinf(ang[2]);
  float Rx[3][3] = {{1, 0, 0}, {0, c0, s0}, {0, -s0, c0}};
  float Ry[3][3] = {{c1, 0, -s1}, {0, 1, 0}, {s1, 0, c1}};
  float Rz[3][3] = {{c2, s2, 0}, {-s2, c2, 0}, {0, 0, 1}};
  float A[3][3], R[3][3];
  for (int i = 0; i < 3; ++i)
    for (int j = 0; j < 3; ++j) {
      float s = 0;
      for (int k = 0; k < 3; ++k) s += Rx[i][k] * Ry[k][j];
      A[i][j] = s;
    }
  for (int i = 0; i < 3; ++i)
    for (int j = 0; j < 3; ++j) {
      float s = 0;
      for (int k = 0; k < 3; ++k) s += A[i][k] * Rz[k][j];
      R[i][j] = s;
    }
  float* o = rt + (size_t)idx * 12;
  for (int i = 0; i < 9; ++i) o[i] = R[i / 3][i % 3];
  for (int i = 0; i < 3; ++i) o[9 + i] = tr[i];
}

// ---------- seq2 = R @ (x - trans), overwrites seqb ----------
__global__ void transform_seq(const float* __restrict__ x, const float* __restrict__ rt,
                              half_t* __restrict__ seqb) {
  int idx = blockIdx.x * 256 + threadIdx.x;
  const int tot = 2 * N_ * T_ * V_;
  if (idx >= tot) return;
  int v = idx % V_; int r = idx / V_;
  int t = r % T_; int r2 = r / T_;
  int n = r2 % N_; int p = r2 / N_;
  const float* o = rt + ((size_t)p * N_ + n) * 12;
  float xv[3];
#pragma unroll
  for (int c = 0; c < 3; ++c)
    xv[c] = x[(((size_t)n * C_ + c) * T_ + t) * (V_ * 2) + v * 2 + p] - o[9 + c];
  size_t base = (((size_t)p * N_ + n) * T_ + t) * XP1_;
#pragma unroll
  for (int i = 0; i < 3; ++i) {
    float s = o[i * 3 + 0] * xv[0] + o[i * 3 + 1] * xv[1] + o[i * 3 + 2] * xv[2];
    seqb[base + i * V_ + v] = (half_t)s;
  }
}

// ---------- maxpool over persons + final FC ----------
__global__ void final_fc(const float* __restrict__ hM2, const float* __restrict__ fcW,
                         const float* __restrict__ fcb, float* __restrict__ out) {
  int n = blockIdx.x;
  __shared__ float hm[H_];
  for (int j = threadIdx.x; j < H_; j += blockDim.x)
    hm[j] = fmaxf(hM2[(size_t)n * H_ + j], hM2[(size_t)(N_ + n) * H_ + j]);
  __syncthreads();
  if (threadIdx.x < NCLS_) {
    float acc = fcb[threadIdx.x];
    for (int j = 0; j < H_; ++j) acc += hm[j] * fcW[threadIdx.x * H_ + j];
    out[n * NCLS_ + threadIdx.x] = acc;
  }
}

extern "C" void kernel_launch(void* const* d_in, const int* in_sizes, int n_in,
                              void* d_out, int out_size, void* d_ws, size_t ws_size,
                              hipStream_t stream) {
  const float* x       = (const float*)d_in[0];
  const float* rot_Wih = (const float*)d_in[1];
  const float* rot_Whh = (const float*)d_in[2];
  const float* rot_bih = (const float*)d_in[3];
  const float* rot_bhh = (const float*)d_in[4];
  const float* rot_fcW = (const float*)d_in[5];
  const float* rot_fcb = (const float*)d_in[6];
  const float* tr_Wih  = (const float*)d_in[7];
  const float* tr_Whh  = (const float*)d_in[8];
  const float* tr_bih  = (const float*)d_in[9];
  const float* tr_bhh  = (const float*)d_in[10];
  const float* tr_fcW  = (const float*)d_in[11];
  const float* tr_fcb  = (const float*)d_in[12];
  const float* m0_Wih  = (const float*)d_in[13];
  const float* m0_Whh  = (const float*)d_in[14];
  const float* m0_bih  = (const float*)d_in[15];
  const float* m0_bhh  = (const float*)d_in[16];
  const float* m1_Wih  = (const float*)d_in[17];
  const float* m1_Whh  = (const float*)d_in[18];
  const float* m1_bih  = (const float*)d_in[19];
  const float* m1_bhh  = (const float*)d_in[20];
  const float* m2_Wih  = (const float*)d_in[21];
  const float* m2_Whh  = (const float*)d_in[22];
  const float* m2_bih  = (const float*)d_in[23];
  const float* m2_bhh  = (const float*)d_in[24];
  const float* fcW     = (const float*)d_in[25];
  const float* fcb     = (const float*)d_in[26];

  char* ws = (char*)d_ws;
  size_t off = 0;
  auto take = [&](size_t b) -> void* {
    void* pp = ws + off;
    off = (off + b + 255) & ~(size_t)255;
    return pp;
  };
  half_t* WC_ROT = (half_t*)take((size_t)G4_ * 352 * 2);
  half_t* WC_TR  = (half_t*)take((size_t)G4_ * 352 * 2);
  half_t* WC_M0  = (half_t*)take((size_t)G4_ * 352 * 2);
  half_t* WC_M1  = (half_t*)take((size_t)G4_ * 512 * 2);
  half_t* WC_M2  = (half_t*)take((size_t)G4_ * 512 * 2);
  float* B_ROT = (float*)take((size_t)G4_ * 4);
  float* B_TR  = (float*)take((size_t)G4_ * 4);
  float* B_M0  = (float*)take((size_t)G4_ * 4);
  float* B_M1  = (float*)take((size_t)G4_ * 4);
  float* B_M2  = (float*)take((size_t)G4_ * 4);
  half_t* SEQB = (half_t*)take((size_t)2 * N_ * T_ * XP1_ * 2);
  float* HL_ROT = (float*)take((size_t)2 * N_ * H_ * 4);
  float* HL_TR  = (float*)take((size_t)2 * N_ * H_ * 4);
  float* HL_M2  = (float*)take((size_t)2 * N_ * H_ * 4);
  float* RT     = (float*)take((size_t)2 * N_ * 12 * 4);
  half_t* RING0 = (half_t*)take((size_t)2 * NRING * H_ * 2);
  half_t* RING1 = (half_t*)take((size_t)2 * NRING * H_ * 2);
  unsigned int* CNT = (unsigned int*)take(32 * sizeof(unsigned int));
  half_t* HS0 = (half_t*)take((size_t)2 * N_ * T_ * H_ * 2);
  half_t* HS1 = (half_t*)take((size_t)2 * N_ * T_ * H_ * 2);

  hipMemsetAsync(CNT, 0, 32 * sizeof(unsigned int), stream);

  // ---- pack weights (fp16) + fused biases ----
  pack_wcat<<<1408, 256, 0, stream>>>(rot_Whh, rot_Wih, rot_bih, rot_bhh, WC_ROT, B_ROT, IN_, 352);
  pack_wcat<<<1408, 256, 0, stream>>>(tr_Whh, tr_Wih, tr_bih, tr_bhh, WC_TR, B_TR, IN_, 352);
  pack_wcat<<<1408, 256, 0, stream>>>(m0_Whh, m0_Wih, m0_bih, m0_bhh, WC_M0, B_M0, IN_, 352);
  pack_wcat<<<2048, 256, 0, stream>>>(m1_Whh, m1_Wih, m1_bih, m1_bhh, WC_M1, B_M1, H_, 512);
  pack_wcat<<<2048, 256, 0, stream>>>(m2_Whh, m2_Wih, m2_bih, m2_bhh, WC_M2, B_M2, H_, 512);

  pack_seq<<<(2 * N_ * T_ * XP1_ + 255) / 256, 256, 0, stream>>>(x, SEQB);

  // ---- phase 1: rot & tr in one 256-WG cooperative launch (MT=2) ----
  lstm_coop<11, 2><<<256, 256, 0, stream>>>(
      WC_ROT, WC_TR, B_ROT, B_TR, SEQB, SEQB, XP1_,
      RING0, RING1, nullptr, nullptr, HL_ROT, HL_TR, CNT, 0u);

  fc3_rot<<<2, 256, 0, stream>>>(HL_ROT, HL_TR, rot_fcW, rot_fcb, tr_fcW, tr_fcb, RT);
  transform_seq<<<(2 * N_ * T_ * V_ + 255) / 256, 256, 0, stream>>>(x, RT, SEQB);

  // ---- stacked main LSTMs (rings reused: t=0 never reads ring) ----
  lstm_coop<11, 1><<<256, 256, 0, stream>>>(
      WC_M0, WC_M0, B_M0, B_M0, SEQB, SEQB, XP1_,
      RING0, RING0, HS0, HS0, nullptr, nullptr, CNT, 2400u);
  lstm_coop<16, 1><<<256, 256, 0, stream>>>(
      WC_M1, WC_M1, B_M1, B_M1, HS0, HS0, H_,
      RING0, RING0, HS1, HS1, nullptr, nullptr, CNT, 4800u);
  lstm_coop<16, 1><<<256, 256, 0, stream>>>(
      WC_M2, WC_M2, B_M2, B_M2, HS1, HS1, H_,
      RING0, RING0, nullptr, nullptr, HL_M2, HL_M2, CNT, 7200u);

  final_fc<<<256, 64, 0, stream>>>(HL_M2, fcW, fcb, (float*)d_out);
}

// Round 3
// 12041.194 us; speedup vs baseline: 2.4023x; 2.1217x over previous
//
#include <hip/hip_runtime.h>
#include <hip/hip_fp16.h>

#define N_ 256
#define C_ 3
#define T_ 300
#define V_ 25
#define H_ 256
#define G4_ 1024   // 4*H
#define IN_ 75
#define XP1_ 96    // padded input-K
#define NCLS_ 60
#define NRING 512  // sample rows per run in ring

typedef _Float16 half_t;
typedef __attribute__((ext_vector_type(8))) _Float16 half8;
typedef __attribute__((ext_vector_type(4))) float f32x4;
typedef __attribute__((ext_vector_type(4))) unsigned int uint4v;
typedef __attribute__((ext_vector_type(2))) unsigned int uint2v;

static_assert(sizeof(half8) == 16, "half8 must be 16B");

__device__ __forceinline__ float tanh_f(float x) {
  x = fminf(fmaxf(x, -15.0f), 15.0f);
  float e = __expf(2.0f * x);
  return (e - 1.0f) / (e + 1.0f);
}

// ---- coherent (IF-level) accesses: bypass non-coherent L1/L2, no fences ----
__device__ __forceinline__ uint4v load16_cc(const void* p) {
  uint4v r;
  asm volatile("global_load_dwordx4 %0, %1, off sc0 sc1" : "=v"(r) : "v"(p));
  return r;
}
__device__ __forceinline__ void store8_cc(void* p, uint2v v) {
  asm volatile("global_store_dwordx2 %0, %1, off sc0 sc1" :: "v"(p), "v"(v) : "memory");
}
__device__ __forceinline__ void waitvm0() {
  asm volatile("s_waitcnt vmcnt(0)" ::: "memory");
}

// ---------- pack [Whh | Wih | 0pad] rows into fp16, bias = bih+bhh ----------
__global__ void pack_wcat(const float* __restrict__ Whh, const float* __restrict__ Wih,
                          const float* __restrict__ bih, const float* __restrict__ bhh,
                          half_t* __restrict__ dstW, float* __restrict__ dstB,
                          int inDim, int Kc) {
  int idx = blockIdx.x * 256 + threadIdx.x;
  int tot = G4_ * Kc;
  if (idx < tot) {
    int row = idx / Kc, k = idx % Kc;
    float v = 0.0f;
    if (k < H_) v = Whh[row * H_ + k];
    else if (k - H_ < inDim) v = Wih[row * inDim + (k - H_)];
    dstW[idx] = (half_t)v;
  }
  if (idx < G4_) dstB[idx] = bih[idx] + bhh[idx];
}

// ---------- pack x -> seqb[p][n][t][96] fp16 ----------
__global__ void pack_seq(const float* __restrict__ x, half_t* __restrict__ seqb) {
  int idx = blockIdx.x * 256 + threadIdx.x;
  const int tot = 2 * N_ * T_ * XP1_;
  if (idx >= tot) return;
  int k = idx % XP1_; int r = idx / XP1_;
  int t = r % T_; int r2 = r / T_;
  int n = r2 % N_; int p = r2 / N_;
  float v = 0.0f;
  if (k < IN_) {
    int c = k / V_, vv = k % V_;
    v = x[(((size_t)n * C_ + c) * T_ + t) * (V_ * 2) + vv * 2 + p];
  }
  seqb[idx] = (half_t)v;
}

// ---------- fence-free group barrier (data goes via sc0sc1; flags relaxed) ----------
__device__ __forceinline__ void group_sync(unsigned int* cnt, unsigned int target) {
  __syncthreads();   // all lanes drained vmcnt before arriving (waitvm0 in caller)
  if (threadIdx.x == 0) {
    __hip_atomic_fetch_add(cnt, 1u, __ATOMIC_RELAXED, __HIP_MEMORY_SCOPE_AGENT);
    int guard = 0;
    while (__hip_atomic_load(cnt, __ATOMIC_RELAXED, __HIP_MEMORY_SCOPE_AGENT) < target) {
      __builtin_amdgcn_s_sleep(4);
      if (++guard > (1 << 22)) break;  // safety net
    }
  }
  __syncthreads();
}

// ---------- cooperative LSTM ----------
// group = 8 members (32-unit gate slices); member m of group g is block m*NGROUPS+g.
// Weight slice (128 rows x Kc fp16) LDS-resident. h exchanged per step through a
// coherent ring[parity][member][NRING][32] + flag barrier. MT=2 (32 samples/WG).
template<int KT, int NGROUPS>
__global__ __launch_bounds__(256, 1) void lstm_coop(
    const half_t* __restrict__ WcatA, const half_t* __restrict__ WcatB,
    const float* __restrict__ biasA, const float* __restrict__ biasB,
    const half_t* __restrict__ xseqA, const half_t* __restrict__ xseqB, int XK,
    half_t* ringA, half_t* ringB,
    half_t* hseqA, half_t* hseqB,
    float* hlastA, float* hlastB,
    unsigned int* cnt, unsigned int baseCnt) {
  constexpr int XKT = KT - 8;
  constexpr int Kc = KT * 32;

  const int member = blockIdx.x / NGROUPS;
  const int gidx   = blockIdx.x % NGROUPS;
  const int run    = gidx >> 4;           // NGROUPS=32: 0/1 ; NGROUPS=16: 0
  const int srow0  = (gidx & 15) * 32;    // run-relative first sample row
  const int u0     = member * 32;

  const half_t* __restrict__ Wcat = run ? WcatB : WcatA;
  const float*  __restrict__ bias = run ? biasB : biasA;
  const half_t* __restrict__ xseq = run ? xseqB : xseqA;
  half_t* ring  = run ? ringB : ringA;
  half_t* hseq  = run ? hseqB : hseqA;
  float*  hlast = run ? hlastB : hlastA;
  unsigned int* mycnt = cnt + gidx * 32;  // 128B-padded counters

  const int tid = threadIdx.x;
  const int lane = tid & 63;
  const int wave = tid >> 6;
  const int col = lane & 15;
  const int khalf = lane >> 4;
  const int klo8 = khalf * 8;

  __shared__ __align__(16) half_t wlds[8 * KT * 64 * 8];  // weight fragments
  __shared__ __align__(16) half_t hx[32 * 256];           // swizzled h rows
  __shared__ __align__(8)  half_t hstage[32 * 32];        // output slice staging

  // ---- one-time: weight slice -> LDS fragment-linear ----
  for (int ci = tid; ci < 8 * KT * 64; ci += 256) {
    int nt = ci / (KT * 64);
    int r2 = ci % (KT * 64);
    int kt = r2 / 64;
    int l = r2 & 63;
    int lrow = nt * 16 + (l & 15);
    int grow = (lrow & 3) * 256 + u0 + (lrow >> 2);
    int k = kt * 32 + (l >> 4) * 8;
    *reinterpret_cast<half8*>(&wlds[(size_t)ci * 8]) =
        *reinterpret_cast<const half8*>(Wcat + (size_t)grow * Kc + k);
  }
  float brg[2];
#pragma unroll
  for (int ntp = 0; ntp < 2; ++ntp) {
    int lrow = (wave * 2 + ntp) * 16 + col;
    brg[ntp] = bias[(lrow & 3) * 256 + u0 + (lrow >> 2)];
  }

  const half_t* xrow0[2];
#pragma unroll
  for (int mt = 0; mt < 2; ++mt)
    xrow0[mt] = xseq + (size_t)(srow0 + mt * 16 + col) * T_ * XK;

  const int mm = tid >> 5;        // staging: member slice to read
  const int si = tid & 31;        // staging: sample within group

  float creg[2][2][4] = {};
  const int g = col & 3;
  __syncthreads();

#pragma unroll 1
  for (int t = 0; t < T_; ++t) {
    const int par = t & 1;

    // ---- stage h_prev into LDS (coherent ring loads, XOR-swizzled store) ----
    if (t > 0) {
      const half_t* rbase =
          ring + ((size_t)((par ^ 1) * 8 + mm) * NRING + srow0 + si) * 32;
      uint4v r0 = load16_cc(rbase);
      uint4v r1 = load16_cc(rbase + 8);
      uint4v r2 = load16_cc(rbase + 16);
      uint4v r3 = load16_cc(rbase + 24);
      // x fragments for this step (normal L2 loads, issued before the drain)
      half8 ax[2][XKT];
#pragma unroll
      for (int mt = 0; mt < 2; ++mt)
#pragma unroll
        for (int kx = 0; kx < XKT; ++kx)
          ax[mt][kx] = *reinterpret_cast<const half8*>(
              xrow0[mt] + (size_t)t * XK + kx * 32 + klo8);
      waitvm0();
      __builtin_amdgcn_sched_barrier(0);
#pragma unroll
      for (int j = 0; j < 4; ++j) {
        int c = mm * 4 + j;
        uint4v val = j == 0 ? r0 : (j == 1 ? r1 : (j == 2 ? r2 : r3));
        *reinterpret_cast<uint4v*>(&hx[si * 256 + ((c ^ (si & 7)) * 8)]) = val;
      }
      __syncthreads();

      // ---- MFMA ----
      f32x4 acc[2][2];
#pragma unroll
      for (int mt = 0; mt < 2; ++mt)
#pragma unroll
        for (int ntp = 0; ntp < 2; ++ntp)
          acc[mt][ntp] = (f32x4){brg[ntp], brg[ntp], brg[ntp], brg[ntp]};
#pragma unroll
      for (int kt = 0; kt < KT; ++kt) {
        half8 a0, a1;
        if (kt < 8) {
          int c = kt * 4 + khalf;
          a0 = *reinterpret_cast<const half8*>(&hx[(col) * 256 + ((c ^ (col & 7)) * 8)]);
          a1 = *reinterpret_cast<const half8*>(&hx[(16 + col) * 256 + ((c ^ (col & 7)) * 8)]);
        } else {
          a0 = ax[0][kt - 8];
          a1 = ax[1][kt - 8];
        }
#pragma unroll
        for (int ntp = 0; ntp < 2; ++ntp) {
          half8 bf = *reinterpret_cast<const half8*>(
              &wlds[(size_t)(((wave * 2 + ntp) * KT + kt) * 64 + lane) * 8]);
          acc[0][ntp] = __builtin_amdgcn_mfma_f32_16x16x32_f16(a0, bf, acc[0][ntp], 0, 0, 0);
          acc[1][ntp] = __builtin_amdgcn_mfma_f32_16x16x32_f16(a1, bf, acc[1][ntp], 0, 0, 0);
        }
      }
      compute_act:
      // ---- activations + cell update ----
#pragma unroll
      for (int mt = 0; mt < 2; ++mt) {
#pragma unroll
        for (int ntp = 0; ntp < 2; ++ntp) {
          int nt = wave * 2 + ntp;
          int ul = nt * 4 + (col >> 2);
#pragma unroll
          for (int r = 0; r < 4; ++r) {
            float v = acc[mt][ntp][r];
            float y = (g == 2) ? 2.0f * v : v;
            float s = 1.0f / (1.0f + __expf(-y));
            float av = (g == 2) ? (2.0f * s - 1.0f) : s;
            float b1 = __shfl_xor(av, 1);
            float b2 = __shfl_xor(av, 2);
            float b3 = __shfl_xor(b1, 2);
            auto pick = [&](int k2) { return k2 == 0 ? av : (k2 == 1 ? b1 : (k2 == 2 ? b2 : b3)); };
            float iv = pick(g), fv = pick(g ^ 1), gv = pick(g ^ 2), ov = pick(g ^ 3);
            float c = fv * creg[mt][ntp][r] + iv * gv;
            creg[mt][ntp][r] = c;
            float h = ov * tanh_f(c);
            if (g == 0) {
              int s_ = mt * 16 + khalf * 4 + r;
              hstage[s_ * 32 + ul] = (half_t)h;
              if (hlast != nullptr && t == T_ - 1)
                hlast[(size_t)(srow0 + s_) * H_ + u0 + ul] = h;
            }
          }
        }
      }
      __syncthreads();
    } else {
      // t == 0: h_prev = 0; same body with zero A-h fragments
      half8 ax[2][XKT];
#pragma unroll
      for (int mt = 0; mt < 2; ++mt)
#pragma unroll
        for (int kx = 0; kx < XKT; ++kx)
          ax[mt][kx] = *reinterpret_cast<const half8*>(
              xrow0[mt] + (size_t)0 * XK + kx * 32 + klo8);
      f32x4 acc[2][2];
#pragma unroll
      for (int mt = 0; mt < 2; ++mt)
#pragma unroll
        for (int ntp = 0; ntp < 2; ++ntp)
          acc[mt][ntp] = (f32x4){brg[ntp], brg[ntp], brg[ntp], brg[ntp]};
#pragma unroll
      for (int kx = 0; kx < XKT; ++kx) {
#pragma unroll
        for (int ntp = 0; ntp < 2; ++ntp) {
          half8 bf = *reinterpret_cast<const half8*>(
              &wlds[(size_t)(((wave * 2 + ntp) * KT + 8 + kx) * 64 + lane) * 8]);
          acc[0][ntp] = __builtin_amdgcn_mfma_f32_16x16x32_f16(ax[0][kx], bf, acc[0][ntp], 0, 0, 0);
          acc[1][ntp] = __builtin_amdgcn_mfma_f32_16x16x32_f16(ax[1][kx], bf, acc[1][ntp], 0, 0, 0);
        }
      }
#pragma unroll
      for (int mt = 0; mt < 2; ++mt) {
#pragma unroll
        for (int ntp = 0; ntp < 2; ++ntp) {
          int nt = wave * 2 + ntp;
          int ul = nt * 4 + (col >> 2);
#pragma unroll
          for (int r = 0; r < 4; ++r) {
            float v = acc[mt][ntp][r];
            float y = (g == 2) ? 2.0f * v : v;
            float s = 1.0f / (1.0f + __expf(-y));
            float av = (g == 2) ? (2.0f * s - 1.0f) : s;
            float b1 = __shfl_xor(av, 1);
            float b2 = __shfl_xor(av, 2);
            float b3 = __shfl_xor(b1, 2);
            auto pick = [&](int k2) { return k2 == 0 ? av : (k2 == 1 ? b1 : (k2 == 2 ? b2 : b3)); };
            float iv = pick(g), fv = pick(g ^ 1), gv = pick(g ^ 2), ov = pick(g ^ 3);
            float c = fv * creg[mt][ntp][r] + iv * gv;
            creg[mt][ntp][r] = c;
            float h = ov * tanh_f(c);
            if (g == 0) {
              int s_ = mt * 16 + khalf * 4 + r;
              hstage[s_ * 32 + ul] = (half_t)h;
            }
          }
        }
      }
      __syncthreads();
    }

    // ---- coalesced write-out: ring (coherent) + hseq (normal) ----
    {
      int s = tid >> 3, part = tid & 7;
      uint2v val = *reinterpret_cast<const uint2v*>(&hstage[s * 32 + part * 4]);
      half_t* rp = ring + ((size_t)(par * 8 + member) * NRING + srow0 + s) * 32 + part * 4;
      store8_cc(rp, val);
      if (hseq)
        *reinterpret_cast<uint2v*>(
            &hseq[((size_t)(srow0 + s) * T_ + t) * H_ + u0 + part * 4]) = val;
    }
    waitvm0();
    if (t < T_ - 1) group_sync(mycnt, baseCnt + 8u * (t + 1));
  }
}

// ---------- angles/trans FC + rotation matrices ----------
__global__ void fc3_rot(const float* __restrict__ hrot, const float* __restrict__ htr,
                        const float* __restrict__ rfcW, const float* __restrict__ rfcb,
                        const float* __restrict__ tfcW, const float* __restrict__ tfcb,
                        float* __restrict__ rt) {
  int idx = blockIdx.x * blockDim.x + threadIdx.x;
  if (idx >= 2 * N_) return;
  const float* h1 = hrot + (size_t)idx * H_;
  const float* h2 = htr + (size_t)idx * H_;
  float ang[3], tr[3];
#pragma unroll
  for (int i = 0; i < 3; ++i) {
    float a = rfcb[i], b = tfcb[i];
    for (int j = 0; j < H_; ++j) { a += h1[j] * rfcW[i * H_ + j]; b += h2[j] * tfcW[i * H_ + j]; }
    ang[i] = a * 3.14159265358979323846f;
    tr[i] = b;
  }
  float c0 = cosf(ang[0]), s0 = sinf(ang[0]);
  float c1 = cosf(ang[1]), s1 = sinf(ang[1]);
  float c2 = cosf(ang[2]), s2 = sinf(ang[2]);
  float Rx[3][3] = {{1, 0, 0}, {0, c0, s0}, {0, -s0, c0}};
  float Ry[3][3] = {{c1, 0, -s1}, {0, 1, 0}, {s1, 0, c1}};
  float Rz[3][3] = {{c2, s2, 0}, {-s2, c2, 0}, {0, 0, 1}};
  float A[3][3], R[3][3];
  for (int i = 0; i < 3; ++i)
    for (int j = 0; j < 3; ++j) {
      float s = 0;
      for (int k = 0; k < 3; ++k) s += Rx[i][k] * Ry[k][j];
      A[i][j] = s;
    }
  for (int i = 0; i < 3; ++i)
    for (int j = 0; j < 3; ++j) {
      float s = 0;
      for (int k = 0; k < 3; ++k) s += A[i][k] * Rz[k][j];
      R[i][j] = s;
    }
  float* o = rt + (size_t)idx * 12;
  for (int i = 0; i < 9; ++i) o[i] = R[i / 3][i % 3];
  for (int i = 0; i < 3; ++i) o[9 + i] = tr[i];
}

// ---------- seq2 = R @ (x - trans), overwrites seqb ----------
__global__ void transform_seq(const float* __restrict__ x, const float* __restrict__ rt,
                              half_t* __restrict__ seqb) {
  int idx = blockIdx.x * 256 + threadIdx.x;
  const int tot = 2 * N_ * T_ * V_;
  if (idx >= tot) return;
  int v = idx % V_; int r = idx / V_;
  int t = r % T_; int r2 = r / T_;
  int n = r2 % N_; int p = r2 / N_;
  const float* o = rt + ((size_t)p * N_ + n) * 12;
  float xv[3];
#pragma unroll
  for (int c = 0; c < 3; ++c)
    xv[c] = x[(((size_t)n * C_ + c) * T_ + t) * (V_ * 2) + v * 2 + p] - o[9 + c];
  size_t base = (((size_t)p * N_ + n) * T_ + t) * XP1_;
#pragma unroll
  for (int i = 0; i < 3; ++i) {
    float s = o[i * 3 + 0] * xv[0] + o[i * 3 + 1] * xv[1] + o[i * 3 + 2] * xv[2];
    seqb[base + i * V_ + v] = (half_t)s;
  }
}

// ---------- maxpool over persons + final FC ----------
__global__ void final_fc(const float* __restrict__ hM2, const float* __restrict__ fcW,
                         const float* __restrict__ fcb, float* __restrict__ out) {
  int n = blockIdx.x;
  __shared__ float hm[H_];
  for (int j = threadIdx.x; j < H_; j += blockDim.x)
    hm[j] = fmaxf(hM2[(size_t)n * H_ + j], hM2[(size_t)(N_ + n) * H_ + j]);
  __syncthreads();
  if (threadIdx.x < NCLS_) {
    float acc = fcb[threadIdx.x];
    for (int j = 0; j < H_; ++j) acc += hm[j] * fcW[threadIdx.x * H_ + j];
    out[n * NCLS_ + threadIdx.x] = acc;
  }
}

extern "C" void kernel_launch(void* const* d_in, const int* in_sizes, int n_in,
                              void* d_out, int out_size, void* d_ws, size_t ws_size,
                              hipStream_t stream) {
  const float* x       = (const float*)d_in[0];
  const float* rot_Wih = (const float*)d_in[1];
  const float* rot_Whh = (const float*)d_in[2];
  const float* rot_bih = (const float*)d_in[3];
  const float* rot_bhh = (const float*)d_in[4];
  const float* rot_fcW = (const float*)d_in[5];
  const float* rot_fcb = (const float*)d_in[6];
  const float* tr_Wih  = (const float*)d_in[7];
  const float* tr_Whh  = (const float*)d_in[8];
  const float* tr_bih  = (const float*)d_in[9];
  const float* tr_bhh  = (const float*)d_in[10];
  const float* tr_fcW  = (const float*)d_in[11];
  const float* tr_fcb  = (const float*)d_in[12];
  const float* m0_Wih  = (const float*)d_in[13];
  const float* m0_Whh  = (const float*)d_in[14];
  const float* m0_bih  = (const float*)d_in[15];
  const float* m0_bhh  = (const float*)d_in[16];
  const float* m1_Wih  = (const float*)d_in[17];
  const float* m1_Whh  = (const float*)d_in[18];
  const float* m1_bih  = (const float*)d_in[19];
  const float* m1_bhh  = (const float*)d_in[20];
  const float* m2_Wih  = (const float*)d_in[21];
  const float* m2_Whh  = (const float*)d_in[22];
  const float* m2_bih  = (const float*)d_in[23];
  const float* m2_bhh  = (const float*)d_in[24];
  const float* fcW     = (const float*)d_in[25];
  const float* fcb     = (const float*)d_in[26];

  char* ws = (char*)d_ws;
  size_t off = 0;
  auto take = [&](size_t b) -> void* {
    void* pp = ws + off;
    off = (off + b + 255) & ~(size_t)255;
    return pp;
  };
  half_t* WC_ROT = (half_t*)take((size_t)G4_ * 352 * 2);
  half_t* WC_TR  = (half_t*)take((size_t)G4_ * 352 * 2);
  half_t* WC_M0  = (half_t*)take((size_t)G4_ * 352 * 2);
  half_t* WC_M1  = (half_t*)take((size_t)G4_ * 512 * 2);
  half_t* WC_M2  = (half_t*)take((size_t)G4_ * 512 * 2);
  float* B_ROT = (float*)take((size_t)G4_ * 4);
  float* B_TR  = (float*)take((size_t)G4_ * 4);
  float* B_M0  = (float*)take((size_t)G4_ * 4);
  float* B_M1  = (float*)take((size_t)G4_ * 4);
  float* B_M2  = (float*)take((size_t)G4_ * 4);
  half_t* SEQB = (half_t*)take((size_t)2 * N_ * T_ * XP1_ * 2);
  float* HL_ROT = (float*)take((size_t)2 * N_ * H_ * 4);
  float* HL_TR  = (float*)take((size_t)2 * N_ * H_ * 4);
  float* HL_M2  = (float*)take((size_t)2 * N_ * H_ * 4);
  float* RT     = (float*)take((size_t)2 * N_ * 12 * 4);
  half_t* RING0 = (half_t*)take((size_t)2 * 8 * NRING * 32 * 2);
  half_t* RING1 = (half_t*)take((size_t)2 * 8 * NRING * 32 * 2);
  unsigned int* CNT = (unsigned int*)take(32 * 32 * sizeof(unsigned int));
  half_t* HS0 = (half_t*)take((size_t)2 * N_ * T_ * H_ * 2);
  half_t* HS1 = (half_t*)take((size_t)2 * N_ * T_ * H_ * 2);

  hipMemsetAsync(CNT, 0, 32 * 32 * sizeof(unsigned int), stream);

  // ---- pack weights (fp16) + fused biases ----
  pack_wcat<<<1408, 256, 0, stream>>>(rot_Whh, rot_Wih, rot_bih, rot_bhh, WC_ROT, B_ROT, IN_, 352);
  pack_wcat<<<1408, 256, 0, stream>>>(tr_Whh, tr_Wih, tr_bih, tr_bhh, WC_TR, B_TR, IN_, 352);
  pack_wcat<<<1408, 256, 0, stream>>>(m0_Whh, m0_Wih, m0_bih, m0_bhh, WC_M0, B_M0, IN_, 352);
  pack_wcat<<<2048, 256, 0, stream>>>(m1_Whh, m1_Wih, m1_bih, m1_bhh, WC_M1, B_M1, H_, 512);
  pack_wcat<<<2048, 256, 0, stream>>>(m2_Whh, m2_Wih, m2_bih, m2_bhh, WC_M2, B_M2, H_, 512);

  pack_seq<<<(2 * N_ * T_ * XP1_ + 255) / 256, 256, 0, stream>>>(x, SEQB);

  // ---- phase 1: rot & tr in one launch (32 groups x 8 members) ----
  lstm_coop<11, 32><<<256, 256, 0, stream>>>(
      WC_ROT, WC_TR, B_ROT, B_TR, SEQB, SEQB, XP1_,
      RING0, RING1, nullptr, nullptr, HL_ROT, HL_TR, CNT, 0u);

  fc3_rot<<<2, 256, 0, stream>>>(HL_ROT, HL_TR, rot_fcW, rot_fcb, tr_fcW, tr_fcb, RT);
  transform_seq<<<(2 * N_ * T_ * V_ + 255) / 256, 256, 0, stream>>>(x, RT, SEQB);

  // ---- stacked main LSTMs (16 groups x 8 members; monotone counters) ----
  lstm_coop<11, 16><<<128, 256, 0, stream>>>(
      WC_M0, WC_M0, B_M0, B_M0, SEQB, SEQB, XP1_,
      RING0, RING0, HS0, HS0, nullptr, nullptr, CNT, 2392u);
  lstm_coop<16, 16><<<128, 256, 0, stream>>>(
      WC_M1, WC_M1, B_M1, B_M1, HS0, HS0, H_,
      RING0, RING0, HS1, HS1, nullptr, nullptr, CNT, 4784u);
  lstm_coop<16, 16><<<128, 256, 0, stream>>>(
      WC_M2, WC_M2, B_M2, B_M2, HS1, HS1, H_,
      RING0, RING0, nullptr, nullptr, HL_M2, HL_M2, CNT, 7176u);

  final_fc<<<256, 64, 0, stream>>>(HL_M2, fcW, fcb, (float*)d_out);
}

// Round 5
// 11883.203 us; speedup vs baseline: 2.4343x; 1.0133x over previous
//
#include <hip/hip_runtime.h>
#include <hip/hip_fp16.h>

#define N_ 256
#define C_ 3
#define T_ 300
#define V_ 25
#define H_ 256
#define G4_ 1024   // 4*H
#define IN_ 75
#define XP1_ 96    // padded input-K
#define NCLS_ 60
#define RROWS 1024 // ring rows (phase-1: 2 runs x 512)

typedef _Float16 half_t;
typedef __attribute__((ext_vector_type(8))) _Float16 half8;
typedef __attribute__((ext_vector_type(4))) float f32x4;
typedef __attribute__((ext_vector_type(4))) unsigned int uint4v;
typedef __attribute__((ext_vector_type(2))) unsigned int uint2v;

static_assert(sizeof(half8) == 16, "half8 must be 16B");

__device__ __forceinline__ float tanh_f(float x) {
  x = fminf(fmaxf(x, -15.0f), 15.0f);
  float e = __expf(2.0f * x);
  return (e - 1.0f) / (e + 1.0f);
}

// ---- coherent (IF-level) ops: bypass non-coherent L1/L2, no fences needed ----
__device__ __forceinline__ half8 gload16_cc(const void* p) {
  uint4v r;
  asm volatile("global_load_dwordx4 %0, %1, off sc0 sc1" : "=v"(r) : "v"(p));
  return __builtin_bit_cast(half8, r);
}
__device__ __forceinline__ void store8_cc(void* p, uint2v v) {
  asm volatile("global_store_dwordx2 %0, %1, off sc0 sc1" :: "v"(p), "v"(v) : "memory");
}
__device__ __forceinline__ void waitvm0() {
  asm volatile("s_waitcnt vmcnt(0)" ::: "memory");
  __builtin_amdgcn_sched_barrier(0);
}

// ---------- pack [Whh | Wih | 0pad] rows into fp16, bias = bih+bhh ----------
__global__ void pack_wcat(const float* __restrict__ Whh, const float* __restrict__ Wih,
                          const float* __restrict__ bih, const float* __restrict__ bhh,
                          half_t* __restrict__ dstW, float* __restrict__ dstB,
                          int inDim, int Kc) {
  int idx = blockIdx.x * 256 + threadIdx.x;
  int tot = G4_ * Kc;
  if (idx < tot) {
    int row = idx / Kc, k = idx % Kc;
    float v = 0.0f;
    if (k < H_) v = Whh[row * H_ + k];
    else if (k - H_ < inDim) v = Wih[row * inDim + (k - H_)];
    dstW[idx] = (half_t)v;
  }
  if (idx < G4_) dstB[idx] = bih[idx] + bhh[idx];
}

// ---------- pack x -> seqb[p][n][t][96] fp16 ----------
__global__ void pack_seq(const float* __restrict__ x, half_t* __restrict__ seqb) {
  int idx = blockIdx.x * 256 + threadIdx.x;
  const int tot = 2 * N_ * T_ * XP1_;
  if (idx >= tot) return;
  int k = idx % XP1_; int r = idx / XP1_;
  int t = r % T_; int r2 = r / T_;
  int n = r2 % N_; int p = r2 / N_;
  float v = 0.0f;
  if (k < IN_) {
    int c = k / V_, vv = k % V_;
    v = x[(((size_t)n * C_ + c) * T_ + t) * (V_ * 2) + vv * 2 + p];
  }
  seqb[idx] = (half_t)v;
}

// ---------- cooperative LSTM, flag-vector barrier ----------
// group g = 32 sample rows; 8 members (32-unit gate slices); member m of group g
// is block m*NGROUPS+g. Weights in VGPRs. h exchanged via coherent ring
// [parity][member][row][32]; per-(group,member) monotone step flags.
template<int KT, int NGROUPS>
__global__ __launch_bounds__(256, 1) void lstm_flag(
    const half_t* __restrict__ W0, const half_t* __restrict__ W1,
    const float* __restrict__ b0, const float* __restrict__ b1,
    const half_t* __restrict__ xseq, int XK,
    half_t* __restrict__ ring, half_t* __restrict__ hseq,
    float* __restrict__ hlast0, float* __restrict__ hlast1,
    unsigned int* __restrict__ flags) {
  constexpr int XKT = KT - 8;
  constexpr int Kc = KT * 32;
  const int member = blockIdx.x / NGROUPS;
  const int g = blockIdx.x % NGROUPS;
  const int run = (NGROUPS == 32) ? (g >> 4) : 0;
  const int ringRow0 = g * 32;
  const int seqRow0 = ringRow0 - run * 512;
  const int u0 = member * 32;

  const half_t* __restrict__ Wcat = run ? W1 : W0;
  const float* __restrict__ bias = run ? b1 : b0;
  float* hlast = run ? hlast1 : hlast0;
  unsigned int* gflag = flags + g * 32;   // 128B-padded per group

  const int tid = threadIdx.x, lane = tid & 63, wave = tid >> 6;
  const int col = lane & 15, khalf = lane >> 4, klo8 = khalf * 8, gq = col & 3;

  __shared__ __align__(8) half_t hstage[32 * 32];

  // ---- weights + bias -> registers (fragment layout as validated) ----
  half8 wreg[2][KT];
  float brg[2];
#pragma unroll
  for (int ntp = 0; ntp < 2; ++ntp) {
    int lrow = (wave * 2 + ntp) * 16 + col;
    int grow = (lrow & 3) * 256 + u0 + (lrow >> 2);
#pragma unroll
    for (int kt = 0; kt < KT; ++kt)
      wreg[ntp][kt] = *reinterpret_cast<const half8*>(Wcat + (size_t)grow * Kc + kt * 32 + klo8);
    brg[ntp] = bias[grow];
  }

  const half_t* xrow[2];
#pragma unroll
  for (int c = 0; c < 2; ++c)
    xrow[c] = xseq + (size_t)(seqRow0 + c * 16 + col) * T_ * XK + klo8;

  float creg[2][2][4] = {};

#pragma unroll 1
  for (int t = 0; t < T_; ++t) {
    // ---- x fragments (normal cached loads; issued before the poll) ----
    half8 ax[2][XKT];
#pragma unroll
    for (int c = 0; c < 2; ++c)
#pragma unroll
      for (int kx = 0; kx < XKT; ++kx)
        ax[c][kx] = *reinterpret_cast<const half8*>(xrow[c] + (size_t)t * XK + kx * 32);

    const bool hasH = (t > 0);
    half8 ah[2][8];
    if (hasH) {
      // ---- poll all 8 member flags in one IF round-trip ----
      if (wave == 0) {
        const unsigned tgt = (unsigned)t;
        int guard = 0;
        for (;;) {
          unsigned f = tgt;
          if (lane < 8)
            f = __hip_atomic_load(&gflag[lane], __ATOMIC_RELAXED, __HIP_MEMORY_SCOPE_AGENT);
          if (__all(f >= tgt)) break;
          __builtin_amdgcn_s_sleep(1);
          if (++guard > (1 << 16)) break;  // safety net
        }
      }
      __syncthreads();
      __builtin_amdgcn_sched_barrier(0);
      const int par = (t - 1) & 1;
#pragma unroll
      for (int c = 0; c < 2; ++c)
#pragma unroll
        for (int kt = 0; kt < 8; ++kt)
          ah[c][kt] = gload16_cc(
              ring + ((size_t)(par * 8 + kt) * RROWS + ringRow0 + c * 16 + col) * 32 + klo8);
    }
    waitvm0();  // all asm loads complete before any MFMA (incl. sched_barrier)

    // ---- MFMA + activations for both 16-row chunks ----
#pragma unroll
    for (int c = 0; c < 2; ++c) {
      f32x4 acc[2];
      acc[0] = (f32x4){brg[0], brg[0], brg[0], brg[0]};
      acc[1] = (f32x4){brg[1], brg[1], brg[1], brg[1]};
      if (hasH) {
#pragma unroll
        for (int kt = 0; kt < 8; ++kt) {
          acc[0] = __builtin_amdgcn_mfma_f32_16x16x32_f16(ah[c][kt], wreg[0][kt], acc[0], 0, 0, 0);
          acc[1] = __builtin_amdgcn_mfma_f32_16x16x32_f16(ah[c][kt], wreg[1][kt], acc[1], 0, 0, 0);
        }
      }
#pragma unroll
      for (int kx = 0; kx < XKT; ++kx) {
        acc[0] = __builtin_amdgcn_mfma_f32_16x16x32_f16(ax[c][kx], wreg[0][8 + kx], acc[0], 0, 0, 0);
        acc[1] = __builtin_amdgcn_mfma_f32_16x16x32_f16(ax[c][kx], wreg[1][8 + kx], acc[1], 0, 0, 0);
      }
#pragma unroll
      for (int ntp = 0; ntp < 2; ++ntp) {
        int nt = wave * 2 + ntp;
        int ul = nt * 4 + (col >> 2);
#pragma unroll
        for (int r = 0; r < 4; ++r) {
          float v = acc[ntp][r];
          float y = (gq == 2) ? 2.0f * v : v;
          float s = 1.0f / (1.0f + __expf(-y));
          float av = (gq == 2) ? (2.0f * s - 1.0f) : s;
          float b1v = __shfl_xor(av, 1);
          float b2v = __shfl_xor(av, 2);
          float b3v = __shfl_xor(b1v, 2);
          auto pick = [&](int k2) { return k2 == 0 ? av : (k2 == 1 ? b1v : (k2 == 2 ? b2v : b3v)); };
          float iv = pick(gq), fv = pick(gq ^ 1), gv = pick(gq ^ 2), ov = pick(gq ^ 3);
          float cc = fv * creg[c][ntp][r] + iv * gv;
          creg[c][ntp][r] = cc;
          float h = ov * tanh_f(cc);
          if (gq == 0) {
            int s_ = c * 16 + khalf * 4 + r;
            hstage[s_ * 32 + ul] = (half_t)h;
            if (hlast != nullptr && t == T_ - 1)
              hlast[(size_t)(seqRow0 + s_) * H_ + u0 + ul] = h;
          }
        }
      }
    }
    __syncthreads();

    // ---- coalesced write-out: ring (coherent) + hseq (normal) ----
    {
      int row = tid >> 3, part = tid & 7;
      uint2v val = *reinterpret_cast<const uint2v*>(&hstage[row * 32 + part * 4]);
      store8_cc(ring + ((size_t)((t & 1) * 8 + member) * RROWS + ringRow0 + row) * 32 + part * 4, val);
      if (hseq)
        *reinterpret_cast<uint2v*>(
            &hseq[((size_t)(seqRow0 + row) * T_ + t) * H_ + u0 + part * 4]) = val;
    }
    if (t < T_ - 1) {
      waitvm0();       // each thread's ring stores acked at IF
      __syncthreads(); // all threads drained
      if (tid == 0)
        __hip_atomic_fetch_add(&gflag[member], 1u, __ATOMIC_RELAXED, __HIP_MEMORY_SCOPE_AGENT);
    }
  }
}

// ---------- angles/trans FC + rotation matrices ----------
__global__ void fc3_rot(const float* __restrict__ hrot, const float* __restrict__ htr,
                        const float* __restrict__ rfcW, const float* __restrict__ rfcb,
                        const float* __restrict__ tfcW, const float* __restrict__ tfcb,
                        float* __restrict__ rt) {
  int idx = blockIdx.x * blockDim.x + threadIdx.x;
  if (idx >= 2 * N_) return;
  const float* h1 = hrot + (size_t)idx * H_;
  const float* h2 = htr + (size_t)idx * H_;
  float ang[3], tr[3];
#pragma unroll
  for (int i = 0; i < 3; ++i) {
    float a = rfcb[i], b = tfcb[i];
    for (int j = 0; j < H_; ++j) { a += h1[j] * rfcW[i * H_ + j]; b += h2[j] * tfcW[i * H_ + j]; }
    ang[i] = a * 3.14159265358979323846f;
    tr[i] = b;
  }
  float c0 = cosf(ang[0]), s0 = sinf(ang[0]);
  float c1 = cosf(ang[1]), s1 = sinf(ang[1]);
  float c2 = cosf(ang[2]), s2 = sinf(ang[2]);
  float Rx[3][3] = {{1, 0, 0}, {0, c0, s0}, {0, -s0, c0}};
  float Ry[3][3] = {{c1, 0, -s1}, {0, 1, 0}, {s1, 0, c1}};
  float Rz[3][3] = {{c2, s2, 0}, {-s2, c2, 0}, {0, 0, 1}};
  float A[3][3], R[3][3];
  for (int i = 0; i < 3; ++i)
    for (int j = 0; j < 3; ++j) {
      float s = 0;
      for (int k = 0; k < 3; ++k) s += Rx[i][k] * Ry[k][j];
      A[i][j] = s;
    }
  for (int i = 0; i < 3; ++i)
    for (int j = 0; j < 3; ++j) {
      float s = 0;
      for (int k = 0; k < 3; ++k) s += A[i][k] * Rz[k][j];
      R[i][j] = s;
    }
  float* o = rt + (size_t)idx * 12;
  for (int i = 0; i < 9; ++i) o[i] = R[i / 3][i % 3];
  for (int i = 0; i < 3; ++i) o[9 + i] = tr[i];
}

// ---------- seq2 = R @ (x - trans), overwrites seqb ----------
__global__ void transform_seq(const float* __restrict__ x, const float* __restrict__ rt,
                              half_t* __restrict__ seqb) {
  int idx = blockIdx.x * 256 + threadIdx.x;
  const int tot = 2 * N_ * T_ * V_;
  if (idx >= tot) return;
  int v = idx % V_; int r = idx / V_;
  int t = r % T_; int r2 = r / T_;
  int n = r2 % N_; int p = r2 / N_;
  const float* o = rt + ((size_t)p * N_ + n) * 12;
  float xv[3];
#pragma unroll
  for (int c = 0; c < 3; ++c)
    xv[c] = x[(((size_t)n * C_ + c) * T_ + t) * (V_ * 2) + v * 2 + p] - o[9 + c];
  size_t base = (((size_t)p * N_ + n) * T_ + t) * XP1_;
#pragma unroll
  for (int i = 0; i < 3; ++i) {
    float s = o[i * 3 + 0] * xv[0] + o[i * 3 + 1] * xv[1] + o[i * 3 + 2] * xv[2];
    seqb[base + i * V_ + v] = (half_t)s;
  }
}

// ---------- maxpool over persons + final FC ----------
__global__ void final_fc(const float* __restrict__ hM2, const float* __restrict__ fcW,
                         const float* __restrict__ fcb, float* __restrict__ out) {
  int n = blockIdx.x;
  __shared__ float hm[H_];
  for (int j = threadIdx.x; j < H_; j += blockDim.x)
    hm[j] = fmaxf(hM2[(size_t)n * H_ + j], hM2[(size_t)(N_ + n) * H_ + j]);
  __syncthreads();
  if (threadIdx.x < NCLS_) {
    float acc = fcb[threadIdx.x];
    for (int j = 0; j < H_; ++j) acc += hm[j] * fcW[threadIdx.x * H_ + j];
    out[n * NCLS_ + threadIdx.x] = acc;
  }
}

extern "C" void kernel_launch(void* const* d_in, const int* in_sizes, int n_in,
                              void* d_out, int out_size, void* d_ws, size_t ws_size,
                              hipStream_t stream) {
  const float* x       = (const float*)d_in[0];
  const float* rot_Wih = (const float*)d_in[1];
  const float* rot_Whh = (const float*)d_in[2];
  const float* rot_bih = (const float*)d_in[3];
  const float* rot_bhh = (const float*)d_in[4];
  const float* rot_fcW = (const float*)d_in[5];
  const float* rot_fcb = (const float*)d_in[6];
  const float* tr_Wih  = (const float*)d_in[7];
  const float* tr_Whh  = (const float*)d_in[8];
  const float* tr_bih  = (const float*)d_in[9];
  const float* tr_bhh  = (const float*)d_in[10];
  const float* tr_fcW  = (const float*)d_in[11];
  const float* tr_fcb  = (const float*)d_in[12];
  const float* m0_Wih  = (const float*)d_in[13];
  const float* m0_Whh  = (const float*)d_in[14];
  const float* m0_bih  = (const float*)d_in[15];
  const float* m0_bhh  = (const float*)d_in[16];
  const float* m1_Wih  = (const float*)d_in[17];
  const float* m1_Whh  = (const float*)d_in[18];
  const float* m1_bih  = (const float*)d_in[19];
  const float* m1_bhh  = (const float*)d_in[20];
  const float* m2_Wih  = (const float*)d_in[21];
  const float* m2_Whh  = (const float*)d_in[22];
  const float* m2_bih  = (const float*)d_in[23];
  const float* m2_bhh  = (const float*)d_in[24];
  const float* fcW     = (const float*)d_in[25];
  const float* fcb     = (const float*)d_in[26];

  char* ws = (char*)d_ws;
  size_t off = 0;
  auto take = [&](size_t b) -> void* {
    void* pp = ws + off;
    off = (off + b + 255) & ~(size_t)255;
    return pp;
  };
  half_t* WC_ROT = (half_t*)take((size_t)G4_ * 352 * 2);
  half_t* WC_TR  = (half_t*)take((size_t)G4_ * 352 * 2);
  half_t* WC_M0  = (half_t*)take((size_t)G4_ * 352 * 2);
  half_t* WC_M1  = (half_t*)take((size_t)G4_ * 512 * 2);
  half_t* WC_M2  = (half_t*)take((size_t)G4_ * 512 * 2);
  float* B_ROT = (float*)take((size_t)G4_ * 4);
  float* B_TR  = (float*)take((size_t)G4_ * 4);
  float* B_M0  = (float*)take((size_t)G4_ * 4);
  float* B_M1  = (float*)take((size_t)G4_ * 4);
  float* B_M2  = (float*)take((size_t)G4_ * 4);
  half_t* SEQB = (half_t*)take((size_t)2 * N_ * T_ * XP1_ * 2);
  float* HL_ROT = (float*)take((size_t)2 * N_ * H_ * 4);
  float* HL_TR  = (float*)take((size_t)2 * N_ * H_ * 4);
  float* HL_M2  = (float*)take((size_t)2 * N_ * H_ * 4);
  float* RT     = (float*)take((size_t)2 * N_ * 12 * 4);
  half_t* RING  = (half_t*)take((size_t)2 * 8 * RROWS * 32 * 2);
  unsigned int* FLAGS = (unsigned int*)take((size_t)128 * 32 * sizeof(unsigned int));
  half_t* HS0 = (half_t*)take((size_t)2 * N_ * T_ * H_ * 2);
  half_t* HS1 = (half_t*)take((size_t)2 * N_ * T_ * H_ * 2);

  hipMemsetAsync(FLAGS, 0, 128 * 32 * sizeof(unsigned int), stream);

  // ---- pack weights (fp16) + fused biases ----
  pack_wcat<<<1408, 256, 0, stream>>>(rot_Whh, rot_Wih, rot_bih, rot_bhh, WC_ROT, B_ROT, IN_, 352);
  pack_wcat<<<1408, 256, 0, stream>>>(tr_Whh, tr_Wih, tr_bih, tr_bhh, WC_TR, B_TR, IN_, 352);
  pack_wcat<<<1408, 256, 0, stream>>>(m0_Whh, m0_Wih, m0_bih, m0_bhh, WC_M0, B_M0, IN_, 352);
  pack_wcat<<<2048, 256, 0, stream>>>(m1_Whh, m1_Wih, m1_bih, m1_bhh, WC_M1, B_M1, H_, 512);
  pack_wcat<<<2048, 256, 0, stream>>>(m2_Whh, m2_Wih, m2_bih, m2_bhh, WC_M2, B_M2, H_, 512);

  pack_seq<<<(2 * N_ * T_ * XP1_ + 255) / 256, 256, 0, stream>>>(x, SEQB);

  // ---- phase 1: rot (run0, rows 0..511) & tr (run1, rows 512..1023) ----
  lstm_flag<11, 32><<<256, 256, 0, stream>>>(
      WC_ROT, WC_TR, B_ROT, B_TR, SEQB, XP1_,
      RING, nullptr, HL_ROT, HL_TR, FLAGS);

  fc3_rot<<<2, 256, 0, stream>>>(HL_ROT, HL_TR, rot_fcW, rot_fcb, tr_fcW, tr_fcb, RT);
  transform_seq<<<(2 * N_ * T_ * V_ + 255) / 256, 256, 0, stream>>>(x, RT, SEQB);

  // ---- stacked main LSTMs (16 groups x 8 members = 128 WGs each) ----
  lstm_flag<11, 16><<<128, 256, 0, stream>>>(
      WC_M0, WC_M0, B_M0, B_M0, SEQB, XP1_,
      RING, HS0, nullptr, nullptr, FLAGS + 32 * 32);
  lstm_flag<16, 16><<<128, 256, 0, stream>>>(
      WC_M1, WC_M1, B_M1, B_M1, HS0, H_,
      RING, HS1, nullptr, nullptr, FLAGS + 48 * 32);
  lstm_flag<16, 16><<<128, 256, 0, stream>>>(
      WC_M2, WC_M2, B_M2, B_M2, HS1, H_,
      RING, nullptr, HL_M2, HL_M2, FLAGS + 64 * 32);

  final_fc<<<256, 64, 0, stream>>>(HL_M2, fcW, fcb, (float*)d_out);
}